// Round 5
// baseline (1246.474 us; speedup 1.0000x reference)
//
#include <hip/hip_runtime.h>

// GRUModel: 2-layer GRU (H=64), B=4096, T=512, fp32 in/out — MFMA round 5.
//
// R5 change vs R4 (840 us, 1 wave/SIMD, ~3.9k cyc/step dominated by exposed
// latency): batch split twice as fine — 512 blocks x 8 rows (M=8 in the
// 16-row MFMA tile; tile rows 8..15 are garbage-but-finite and never stored).
// 2 blocks/CU -> 2 waves/SIMD from INDEPENDENT blocks (independent barriers):
// one block's barrier/LDS-latency window is filled by the other block's
// issue. LDS ~37 KB/block -> 74 KB/CU.
//
// Structure (unchanged from R4): per block 4 waves, wave w owns units
// u=16w..16w+15 for all 3 gates (gates lane-local in C-layout); h-state fp32
// in registers; split-fp16 2-product MFMA (D = (Ah+Al)@Bh, weights single
// fp16); planar fp16 LDS h-planes (stride 72, 16B-aligned b128 A-frag reads);
// ONE barrier per step under parity double-buffering.
//
// Frag layouts (m89/m120-verified, dtype-independent):
//   A: lane holds A[m=lane&15][k=(lane>>4)*8+j], j=0..7
//   B: lane holds B[k=(lane>>4)*8+j][n=lane&15]
//   C/D: lane holds D[m=(lane>>4)*4+reg][n=lane&15]

typedef _Float16 half8 __attribute__((ext_vector_type(8)));
typedef float    v4f   __attribute__((ext_vector_type(4)));

#define T_LEN 512
#define MROWS 8   // real batch rows per block
#define KS 72     // fp16-element row stride of h planes (16B-aligned reads)
#define XSS 9     // xs row stride (fp32)

static __device__ __forceinline__ float sigm(float x) {
    return 1.0f / (1.0f + __expf(-x));
}
static __device__ __forceinline__ float tanh_fast(float x) {
    return 2.0f / (1.0f + __expf(-2.0f * x)) - 1.0f;
}
static __device__ __forceinline__ v4f mfma16(half8 a, half8 b, v4f c) {
    return __builtin_amdgcn_mfma_f32_16x16x32_f16(a, b, c, 0, 0, 0);
}
static __device__ __forceinline__ half8 ld8(const _Float16* p) {
    return *(const half8*)p;
}

__global__ __launch_bounds__(256, 1)
void gru_mfma(const float* __restrict__ x,
              const float* __restrict__ w_ih0, const float* __restrict__ w_hh0,
              const float* __restrict__ b_ih0, const float* __restrict__ b_hh0,
              const float* __restrict__ w_ih1, const float* __restrict__ w_hh1,
              const float* __restrict__ b_ih1, const float* __restrict__ b_hh1,
              const float* __restrict__ fc_w,  const float* __restrict__ fc_b,
              float* __restrict__ out)
{
    __shared__ __align__(16) float xs[T_LEN * XSS];           // x[t][m], 8 rows
    __shared__ __align__(16) _Float16 h0hi[2][16 * KS];       // h planes, 2 parities
    __shared__ __align__(16) _Float16 h0lo[2][16 * KS];
    __shared__ __align__(16) _Float16 h1hi[2][16 * KS];
    __shared__ __align__(16) _Float16 h1lo[2][16 * KS];
    __shared__ float red[64];

    const int tid  = threadIdx.x;
    const int w    = tid >> 6;      // wave id = N-split
    const int lane = tid & 63;
    const int n    = lane & 15;
    const int q    = lane >> 4;
    const int u    = w * 16 + n;    // unit owned in gate phase
    const int mrow = (4 * q) & 7;   // xs row base, clamped for garbage q>=2

    // ---- stage this block's 8 x-rows into LDS (coalesced over t) ----
    const float* xg = x + (size_t)(blockIdx.x * MROWS) * T_LEN;
    for (int i = tid; i < MROWS * T_LEN; i += 256) {
        const int row = i >> 9, t = i & 511;
        xs[t * XSS + row] = xg[row * T_LEN + t];
    }
    for (int i = tid; i < 16 * KS; i += 256) {
        h0hi[0][i] = (_Float16)0; h0lo[0][i] = (_Float16)0;
        h1hi[0][i] = (_Float16)0; h1lo[0][i] = (_Float16)0;
    }

    // ---- loop-invariant weight B-fragments (single fp16) into VGPRs ----
    half8 B0[3][2];   // W_hh0, K=64 -> 2 chunks
    half8 B1[3][4];   // [W_ih1 (c=0,1) | W_hh1 (c=2,3)], K=128 -> 4 chunks
    {
        const int rows[3] = {u, 64 + u, 128 + u};
        #pragma unroll
        for (int g = 0; g < 3; g++) {
            #pragma unroll
            for (int c = 0; c < 2; c++) {
                const float* r0 = w_hh0 + rows[g] * 64 + 32 * c + 8 * q;
                #pragma unroll
                for (int j = 0; j < 8; j++) B0[g][c][j] = (_Float16)r0[j];
            }
            #pragma unroll
            for (int c = 0; c < 4; c++) {
                const float* M = (c < 2) ? w_ih1 : w_hh1;
                const float* r0 = M + rows[g] * 64 + 32 * (c & 1) + 8 * q;
                #pragma unroll
                for (int j = 0; j < 8; j++) B1[g][c][j] = (_Float16)r0[j];
            }
        }
    }

    // per-lane gate constants (for unit u)
    const float wir = w_ih0[u], wiz = w_ih0[64 + u], win = w_ih0[128 + u];
    const float br0 = b_ih0[u] + b_hh0[u];
    const float bz0 = b_ih0[64 + u] + b_hh0[64 + u];
    const float bin0 = b_ih0[128 + u], bhn0 = b_hh0[128 + u];
    const float br1 = b_ih1[u] + b_hh1[u];
    const float bz1 = b_ih1[64 + u] + b_hh1[64 + u];
    const float bin1 = b_ih1[128 + u], bhn1 = b_hh1[128 + u];

    float h0st[4] = {0.f, 0.f, 0.f, 0.f};   // fp32 h0[m=4q+reg][u]
    float h1st[4] = {0.f, 0.f, 0.f, 0.f};

    __syncthreads();

    const int abase = n * KS + 8 * q;       // A-frag base (fp16 elems)

    #pragma unroll 1
    for (int t = 0; t < T_LEN; t++) {
        const int pr = t & 1, pw = pr ^ 1;

        // A-frags of h0[t-1] (parity pr; written pre-barrier@t-1 -> safe)
        const half8 a0h0 = ld8(&h0hi[pr][abase]);
        const half8 a0h1 = ld8(&h0hi[pr][abase + 32]);
        const half8 a0l0 = ld8(&h0lo[pr][abase]);
        const half8 a0l1 = ld8(&h0lo[pr][abase + 32]);

        float xv[4];
        #pragma unroll
        for (int r = 0; r < 4; r++) xv[r] = xs[t * XSS + ((mrow + r) & 7)];

        // ======== layer 0: G0 = (h0hi+h0lo) @ W_hh0^T + x-rank1 + biases ====
        v4f accR, accZ, accN;
        #pragma unroll
        for (int r = 0; r < 4; r++) {
            accR[r] = fmaf(xv[r], wir, br0);
            accZ[r] = fmaf(xv[r], wiz, bz0);
            accN[r] = 0.f;
        }
        accR = mfma16(a0h0, B0[0][0], accR);
        accZ = mfma16(a0h0, B0[1][0], accZ);
        accN = mfma16(a0h0, B0[2][0], accN);
        accR = mfma16(a0h1, B0[0][1], accR);
        accZ = mfma16(a0h1, B0[1][1], accZ);
        accN = mfma16(a0h1, B0[2][1], accN);
        accR = mfma16(a0l0, B0[0][0], accR);
        accZ = mfma16(a0l0, B0[1][0], accZ);
        accN = mfma16(a0l0, B0[2][0], accN);
        accR = mfma16(a0l1, B0[0][1], accR);
        accZ = mfma16(a0l1, B0[1][1], accZ);
        accN = mfma16(a0l1, B0[2][1], accN);

        #pragma unroll
        for (int r = 0; r < 4; r++) {
            const float rg = sigm(accR[r]);
            const float zg = sigm(accZ[r]);
            const float inn = fmaf(xv[r], win, bin0);
            const float ng = tanh_fast(inn + rg * (accN[r] + bhn0));
            const float h = ng + zg * (h0st[r] - ng);
            h0st[r] = h;
            const _Float16 ah = (_Float16)h;
            const _Float16 al = (_Float16)(h - (float)ah);
            h0hi[pw][(4 * q + r) * KS + u] = ah;
            h0lo[pw][(4 * q + r) * KS + u] = al;
        }

        __syncthreads();   // the ONE barrier per step

        // ======== layer 1: G1 = [h0new | h1] @ [W_ih1 ; W_hh1]^T ========
        const half8 g0h0 = ld8(&h0hi[pw][abase]);
        const half8 g0h1 = ld8(&h0hi[pw][abase + 32]);
        const half8 g0l0 = ld8(&h0lo[pw][abase]);
        const half8 g0l1 = ld8(&h0lo[pw][abase + 32]);
        const half8 g1h0 = ld8(&h1hi[pr][abase]);
        const half8 g1h1 = ld8(&h1hi[pr][abase + 32]);
        const half8 g1l0 = ld8(&h1lo[pr][abase]);
        const half8 g1l1 = ld8(&h1lo[pr][abase + 32]);

        v4f aRi, aZi, aNi, aRh, aZh, aNh;
        #pragma unroll
        for (int r = 0; r < 4; r++) {
            aRi[r] = br1;  aZi[r] = bz1;  aNi[r] = bin1;
            aRh[r] = 0.f;  aZh[r] = 0.f;  aNh[r] = bhn1;
        }
        aRi = mfma16(g0h0, B1[0][0], aRi);
        aZi = mfma16(g0h0, B1[1][0], aZi);
        aNi = mfma16(g0h0, B1[2][0], aNi);
        aRh = mfma16(g1h0, B1[0][2], aRh);
        aZh = mfma16(g1h0, B1[1][2], aZh);
        aNh = mfma16(g1h0, B1[2][2], aNh);
        aRi = mfma16(g0h1, B1[0][1], aRi);
        aZi = mfma16(g0h1, B1[1][1], aZi);
        aNi = mfma16(g0h1, B1[2][1], aNi);
        aRh = mfma16(g1h1, B1[0][3], aRh);
        aZh = mfma16(g1h1, B1[1][3], aZh);
        aNh = mfma16(g1h1, B1[2][3], aNh);
        aRi = mfma16(g0l0, B1[0][0], aRi);
        aZi = mfma16(g0l0, B1[1][0], aZi);
        aNi = mfma16(g0l0, B1[2][0], aNi);
        aRh = mfma16(g1l0, B1[0][2], aRh);
        aZh = mfma16(g1l0, B1[1][2], aZh);
        aNh = mfma16(g1l0, B1[2][2], aNh);
        aRi = mfma16(g0l1, B1[0][1], aRi);
        aZi = mfma16(g0l1, B1[1][1], aZi);
        aNi = mfma16(g0l1, B1[2][1], aNi);
        aRh = mfma16(g1l1, B1[0][3], aRh);
        aZh = mfma16(g1l1, B1[1][3], aZh);
        aNh = mfma16(g1l1, B1[2][3], aNh);

        #pragma unroll
        for (int r = 0; r < 4; r++) {
            const float rg = sigm(aRi[r] + aRh[r]);
            const float zg = sigm(aZi[r] + aZh[r]);
            const float ng = tanh_fast(aNi[r] + rg * aNh[r]);
            const float h = ng + zg * (h1st[r] - ng);
            h1st[r] = h;
            const _Float16 ah = (_Float16)h;
            const _Float16 al = (_Float16)(h - (float)ah);
            h1hi[pw][(4 * q + r) * KS + u] = ah;
            h1lo[pw][(4 * q + r) * KS + u] = al;
        }
        // no second barrier: next step's h1 readers sit behind barrier@t+1
    }

    // ======== FC epilogue: out[m] = sum_u fc_w[u] h1[m][u] + fc_b ========
    const float fw = fc_w[u];
    #pragma unroll
    for (int r = 0; r < 4; r++) {
        float v = fw * h1st[r];
        v += __shfl_xor(v, 1, 64);
        v += __shfl_xor(v, 2, 64);
        v += __shfl_xor(v, 4, 64);
        v += __shfl_xor(v, 8, 64);     // sum over 16 n-lanes (q preserved)
        if (n == 0) red[(4 * q + r) * 4 + w] = v;
    }
    __syncthreads();
    if (tid < MROWS) {
        const float s = red[tid * 4] + red[tid * 4 + 1] + red[tid * 4 + 2] + red[tid * 4 + 3];
        out[blockIdx.x * MROWS + tid] = s + fc_b[0];
    }
}

extern "C" void kernel_launch(void* const* d_in, const int* in_sizes, int n_in,
                              void* d_out, int out_size, void* d_ws, size_t ws_size,
                              hipStream_t stream)
{
    const float* x     = (const float*)d_in[0];
    const float* w_ih0 = (const float*)d_in[1];
    const float* w_hh0 = (const float*)d_in[2];
    const float* b_ih0 = (const float*)d_in[3];
    const float* b_hh0 = (const float*)d_in[4];
    const float* w_ih1 = (const float*)d_in[5];
    const float* w_hh1 = (const float*)d_in[6];
    const float* b_ih1 = (const float*)d_in[7];
    const float* b_hh1 = (const float*)d_in[8];
    const float* fc_w  = (const float*)d_in[9];
    const float* fc_b  = (const float*)d_in[10];
    float* out = (float*)d_out;

    hipLaunchKernelGGL(gru_mfma, dim3(4096 / MROWS), dim3(256), 0, stream,
                       x, w_ih0, w_hh0, b_ih0, b_hh0,
                       w_ih1, w_hh1, b_ih1, b_hh1, fc_w, fc_b, out);
}

// Round 6
// 691.049 us; speedup vs baseline: 1.8037x; 1.8037x over previous
//
#include <hip/hip_runtime.h>

// GRUModel: 2-layer GRU (H=64), B=4096, T=512, fp32 in/out — MFMA round 6.
//
// R6: layer-pipelined wave specialization. 256 blocks x 512 threads (8 waves).
// Waves 0-3 ("L0 group") compute layer 0 at window k; waves 4-7 ("L1 group")
// compute layer 1 at step k-1 in the same window. One barrier per window.
// Per-CU work identical to R4 (144 mfma/step for 16 rows) but 2 independent
// waves/SIMD hide each other's latency (R5 measured marginal fill ~1900 cyc).
//
// Numerics unchanged from R4: split-fp16 2-product (D=(Ah+Al)@Bh, weights
// single fp16), fp32 h-state in registers, absmax 4.9e-4.
//
// Pipeline hazards (parity = step & 1, one barrier per window):
//   L0@k writes h0[k&1], reads h0[(k-1)&1]           (disjoint parities)
//   L1@k (t=k-1) reads h0[t&1] (written window k-1), h1[(t-1)&1] (window k-1),
//          writes h1[t&1] (read in window k+1)       -> all pairs 1 barrier apart
//
// Frag layouts (m89/m120-verified):
//   A: lane holds A[m=lane&15][k=(lane>>4)*8+j], j=0..7
//   B: lane holds B[k=(lane>>4)*8+j][n=lane&15]
//   C/D: lane holds D[m=(lane>>4)*4+reg][n=lane&15]

typedef _Float16 half8 __attribute__((ext_vector_type(8)));
typedef float    v4f   __attribute__((ext_vector_type(4)));

#define T_LEN 512
#define KS 72   // fp16-element row stride of h planes (16B-aligned b128 reads)

static __device__ __forceinline__ float sigm(float x) {
    return 1.0f / (1.0f + __expf(-x));
}
static __device__ __forceinline__ float tanh_fast(float x) {
    return 2.0f / (1.0f + __expf(-2.0f * x)) - 1.0f;
}
static __device__ __forceinline__ v4f mfma16(half8 a, half8 b, v4f c) {
    return __builtin_amdgcn_mfma_f32_16x16x32_f16(a, b, c, 0, 0, 0);
}
static __device__ __forceinline__ half8 ld8(const _Float16* p) {
    return *(const half8*)p;
}

__global__ __launch_bounds__(512, 1)
void gru_mfma(const float* __restrict__ x,
              const float* __restrict__ w_ih0, const float* __restrict__ w_hh0,
              const float* __restrict__ b_ih0, const float* __restrict__ b_hh0,
              const float* __restrict__ w_ih1, const float* __restrict__ w_hh1,
              const float* __restrict__ b_ih1, const float* __restrict__ b_hh1,
              const float* __restrict__ fc_w,  const float* __restrict__ fc_b,
              float* __restrict__ out)
{
    __shared__ __align__(16) float xs[T_LEN * 16];            // [t][m], 32 KB
    __shared__ __align__(16) _Float16 h0hi[2][16 * KS];       // h planes, 2 parities
    __shared__ __align__(16) _Float16 h0lo[2][16 * KS];
    __shared__ __align__(16) _Float16 h1hi[2][16 * KS];
    __shared__ __align__(16) _Float16 h1lo[2][16 * KS];
    __shared__ float red[64];

    const int tid  = threadIdx.x;
    const int wv   = tid >> 6;
    const int grp  = wv >> 2;       // 0 = layer-0 group, 1 = layer-1 group
    const int w    = wv & 3;        // N-split within group
    const int lane = tid & 63;
    const int n    = lane & 15;
    const int q    = lane >> 4;
    const int u    = w * 16 + n;    // unit owned in gate phase

    // ---- stage this block's 16 x-rows into LDS as [t][m] (coalesced) ----
    const float* xg = x + (size_t)(blockIdx.x * 16) * T_LEN;
    for (int i = tid; i < 16 * T_LEN; i += 512) {
        const int row = i >> 9, t = i & 511;
        xs[t * 16 + row] = xg[row * T_LEN + t];
    }
    // zero parity-1 buffers (read by L0@k=0 and L1@k=1 before first write)
    for (int i = tid; i < 16 * KS; i += 512) {
        h0hi[1][i] = (_Float16)0; h0lo[1][i] = (_Float16)0;
        h1hi[1][i] = (_Float16)0; h1lo[1][i] = (_Float16)0;
    }

    // ---- loop-invariant weight B-fragments (single fp16), group-specific ----
    // B[g][c]: grp0 uses c=0,1 (W_hh0, K=64); grp1 uses c=0..3 ([W_ih1|W_hh1])
    half8 B[3][4];
    {
        const int rows[3] = {u, 64 + u, 128 + u};
        const float* bc[4];
        if (grp == 0) {
            bc[0] = w_hh0;      bc[1] = w_hh0 + 32;
            bc[2] = w_hh0;      bc[3] = w_hh0 + 32;   // unused dups
        } else {
            bc[0] = w_ih1;      bc[1] = w_ih1 + 32;
            bc[2] = w_hh1;      bc[3] = w_hh1 + 32;
        }
        #pragma unroll
        for (int g = 0; g < 3; g++)
            #pragma unroll
            for (int c = 0; c < 4; c++) {
                const float* r0 = bc[c] + rows[g] * 64 + 8 * q;
                #pragma unroll
                for (int j = 0; j < 8; j++) B[g][c][j] = (_Float16)r0[j];
            }
    }

    // per-lane gate constants for unit u (group-specific)
    float wir = 0.f, wiz = 0.f, win = 0.f, brc = 0.f, bzc = 0.f, binc = 0.f, bhnc = 0.f;
    if (grp == 0) {
        wir = w_ih0[u]; wiz = w_ih0[64 + u]; win = w_ih0[128 + u];
        brc = b_ih0[u] + b_hh0[u];
        bzc = b_ih0[64 + u] + b_hh0[64 + u];
        binc = b_ih0[128 + u]; bhnc = b_hh0[128 + u];
    } else {
        brc = b_ih1[u] + b_hh1[u];
        bzc = b_ih1[64 + u] + b_hh1[64 + u];
        binc = b_ih1[128 + u]; bhnc = b_hh1[128 + u];
    }

    float hst[4] = {0.f, 0.f, 0.f, 0.f};   // fp32 h[m=4q+reg][u] (own layer)

    __syncthreads();

    const int abase = n * KS + 8 * q;       // A-frag base (fp16 elems)

    #pragma unroll 1
    for (int k = 0; k < T_LEN + 1; k++) {
        if (grp == 0) {
            if (k < T_LEN) {
                const int pw = k & 1, pr = pw ^ 1;
                // A-frags of h0(k-1)
                const half8 a0h0 = ld8(&h0hi[pr][abase]);
                const half8 a0h1 = ld8(&h0hi[pr][abase + 32]);
                const half8 a0l0 = ld8(&h0lo[pr][abase]);
                const half8 a0l1 = ld8(&h0lo[pr][abase + 32]);
                const v4f xv = *(const v4f*)(xs + k * 16 + 4 * q);  // broadcast

                v4f accR, accZ, accN;
                #pragma unroll
                for (int r = 0; r < 4; r++) {
                    accR[r] = fmaf(xv[r], wir, brc);
                    accZ[r] = fmaf(xv[r], wiz, bzc);
                    accN[r] = 0.f;
                }
                accR = mfma16(a0h0, B[0][0], accR);
                accZ = mfma16(a0h0, B[1][0], accZ);
                accN = mfma16(a0h0, B[2][0], accN);
                accR = mfma16(a0h1, B[0][1], accR);
                accZ = mfma16(a0h1, B[1][1], accZ);
                accN = mfma16(a0h1, B[2][1], accN);
                accR = mfma16(a0l0, B[0][0], accR);
                accZ = mfma16(a0l0, B[1][0], accZ);
                accN = mfma16(a0l0, B[2][0], accN);
                accR = mfma16(a0l1, B[0][1], accR);
                accZ = mfma16(a0l1, B[1][1], accZ);
                accN = mfma16(a0l1, B[2][1], accN);

                #pragma unroll
                for (int r = 0; r < 4; r++) {
                    const float rg = sigm(accR[r]);
                    const float zg = sigm(accZ[r]);
                    const float inn = fmaf(xv[r], win, binc);
                    const float ng = tanh_fast(inn + rg * (accN[r] + bhnc));
                    const float h = ng + zg * (hst[r] - ng);
                    hst[r] = h;
                    const _Float16 ah = (_Float16)h;
                    const _Float16 al = (_Float16)(h - (float)ah);
                    h0hi[pw][(4 * q + r) * KS + u] = ah;
                    h0lo[pw][(4 * q + r) * KS + u] = al;
                }
            }
        } else {
            if (k > 0) {
                const int t = k - 1;
                const int pw = t & 1;       // h1(t) write parity; h0(t) parity too
                const int p1 = pw ^ 1;      // h1(t-1) parity
                const half8 g0h0 = ld8(&h0hi[pw][abase]);
                const half8 g0h1 = ld8(&h0hi[pw][abase + 32]);
                const half8 g0l0 = ld8(&h0lo[pw][abase]);
                const half8 g0l1 = ld8(&h0lo[pw][abase + 32]);
                const half8 g1h0 = ld8(&h1hi[p1][abase]);
                const half8 g1h1 = ld8(&h1hi[p1][abase + 32]);
                const half8 g1l0 = ld8(&h1lo[p1][abase]);
                const half8 g1l1 = ld8(&h1lo[p1][abase + 32]);

                v4f aRi, aZi, aNi, aRh, aZh, aNh;
                #pragma unroll
                for (int r = 0; r < 4; r++) {
                    aRi[r] = brc;  aZi[r] = bzc;  aNi[r] = binc;
                    aRh[r] = 0.f;  aZh[r] = 0.f;  aNh[r] = bhnc;
                }
                aRi = mfma16(g0h0, B[0][0], aRi);
                aZi = mfma16(g0h0, B[1][0], aZi);
                aNi = mfma16(g0h0, B[2][0], aNi);
                aRh = mfma16(g1h0, B[0][2], aRh);
                aZh = mfma16(g1h0, B[1][2], aZh);
                aNh = mfma16(g1h0, B[2][2], aNh);
                aRi = mfma16(g0h1, B[0][1], aRi);
                aZi = mfma16(g0h1, B[1][1], aZi);
                aNi = mfma16(g0h1, B[2][1], aNi);
                aRh = mfma16(g1h1, B[0][3], aRh);
                aZh = mfma16(g1h1, B[1][3], aZh);
                aNh = mfma16(g1h1, B[2][3], aNh);
                aRi = mfma16(g0l0, B[0][0], aRi);
                aZi = mfma16(g0l0, B[1][0], aZi);
                aNi = mfma16(g0l0, B[2][0], aNi);
                aRh = mfma16(g1l0, B[0][2], aRh);
                aZh = mfma16(g1l0, B[1][2], aZh);
                aNh = mfma16(g1l0, B[2][2], aNh);
                aRi = mfma16(g0l1, B[0][1], aRi);
                aZi = mfma16(g0l1, B[1][1], aZi);
                aNi = mfma16(g0l1, B[2][1], aNi);
                aRh = mfma16(g1l1, B[0][3], aRh);
                aZh = mfma16(g1l1, B[1][3], aZh);
                aNh = mfma16(g1l1, B[2][3], aNh);

                #pragma unroll
                for (int r = 0; r < 4; r++) {
                    const float rg = sigm(aRi[r] + aRh[r]);
                    const float zg = sigm(aZi[r] + aZh[r]);
                    const float ng = tanh_fast(aNi[r] + rg * aNh[r]);
                    const float h = ng + zg * (hst[r] - ng);
                    hst[r] = h;
                    const _Float16 ah = (_Float16)h;
                    const _Float16 al = (_Float16)(h - (float)ah);
                    h1hi[pw][(4 * q + r) * KS + u] = ah;
                    h1lo[pw][(4 * q + r) * KS + u] = al;
                }
            }
        }
        __syncthreads();   // the ONE barrier per window
    }

    // ======== FC epilogue: out[m] = sum_u fc_w[u] h1[m][u] + fc_b ========
    if (grp == 1) {
        const float fw = fc_w[u];
        #pragma unroll
        for (int r = 0; r < 4; r++) {
            float v = fw * hst[r];
            v += __shfl_xor(v, 1, 64);
            v += __shfl_xor(v, 2, 64);
            v += __shfl_xor(v, 4, 64);
            v += __shfl_xor(v, 8, 64);   // sum over 16 n-lanes (q preserved)
            if (n == 0) red[(4 * q + r) * 4 + w] = v;
        }
    }
    __syncthreads();
    if (tid < 16) {
        const float s = red[tid * 4] + red[tid * 4 + 1] + red[tid * 4 + 2] + red[tid * 4 + 3];
        out[blockIdx.x * 16 + tid] = s + fc_b[0];
    }
}

extern "C" void kernel_launch(void* const* d_in, const int* in_sizes, int n_in,
                              void* d_out, int out_size, void* d_ws, size_t ws_size,
                              hipStream_t stream)
{
    const float* x     = (const float*)d_in[0];
    const float* w_ih0 = (const float*)d_in[1];
    const float* w_hh0 = (const float*)d_in[2];
    const float* b_ih0 = (const float*)d_in[3];
    const float* b_hh0 = (const float*)d_in[4];
    const float* w_ih1 = (const float*)d_in[5];
    const float* w_hh1 = (const float*)d_in[6];
    const float* b_ih1 = (const float*)d_in[7];
    const float* b_hh1 = (const float*)d_in[8];
    const float* fc_w  = (const float*)d_in[9];
    const float* fc_b  = (const float*)d_in[10];
    float* out = (float*)d_out;

    hipLaunchKernelGGL(gru_mfma, dim3(256), dim3(512), 0, stream,
                       x, w_ih0, w_hh0, b_ih0, b_hh0,
                       w_ih1, w_hh1, b_ih1, b_hh1, fc_w, fc_b, out);
}